// Round 3
// baseline (523.858 us; speedup 1.0000x reference)
//
#include <hip/hip_runtime.h>

#define DIMM 512
#define NHEADS 8
#define DHEAD 64
#define QG 4
#define NTOK 1024
#define NROWS (QG * NTOK)      // 4096
#define MALL (3 * NROWS)       // 12288
#define LN_EPSF 1e-5f
#define COS_EPSF 1e-8f
#define LAMBDA_REGF 0.1f

// ---------------------------------------------------------------------------
// Kernel 1: LayerNorm row statistics for q,k,v (rows stacked: [q;k;v])
// one wave (64 lanes) per row of 512 elements
// ---------------------------------------------------------------------------
__global__ __launch_bounds__(256) void ln_stats_kernel(
    const float* __restrict__ q, const float* __restrict__ k,
    const float* __restrict__ v, float* __restrict__ stats) {
  int wave = threadIdx.x >> 6;
  int lane = threadIdx.x & 63;
  int row = blockIdx.x * 4 + wave;  // 0..12287
  const float* src = (row < NROWS) ? q : (row < 2 * NROWS ? k : v);
  int r = row & (NROWS - 1);
  const float* p = src + (size_t)r * DIMM;
  float s = 0.f, ss = 0.f;
#pragma unroll
  for (int i = 0; i < DIMM / 64; ++i) {
    float x = p[lane + i * 64];
    s += x;
    ss += x * x;
  }
#pragma unroll
  for (int off = 32; off; off >>= 1) {
    s += __shfl_xor(s, off);
    ss += __shfl_xor(ss, off);
  }
  if (lane == 0) {
    float mu = s * (1.f / DIMM);
    float var = ss * (1.f / DIMM) - mu * mu;
    stats[row * 2] = mu;
    stats[row * 2 + 1] = rsqrtf(var + LN_EPSF);
  }
}

// ---------------------------------------------------------------------------
// Kernel 2: projection GEMM with fused LayerNorm.
// C[12288][512] = LN(A)[12288][512] @ W_in[512][512]
// 64x64 tile, BK=32, 256 threads, 4x4 micro-tile.
// A-tile stored TRANSPOSED in LDS (sAT[kk][row]): inner-loop A read is a
// float4 broadcast (conflict-free); B read is 2-way-aliased b128 (free).
// ---------------------------------------------------------------------------
__global__ __launch_bounds__(256) void proj_gemm_kernel(
    const float* __restrict__ q, const float* __restrict__ k,
    const float* __restrict__ v, const float* __restrict__ stats,
    const float* __restrict__ ln_g, const float* __restrict__ ln_b,
    const float* __restrict__ W, float* __restrict__ F) {
  __shared__ float sAT[32][72];  // [kk][row], 72*4B=288B row pitch (16B-aligned)
  __shared__ float sB[32][68];
  int row0 = blockIdx.x * 64;
  int col0 = blockIdx.y * 64;
  int tx = threadIdx.x & 15;
  int ty = threadIdx.x >> 4;
  float acc[4][4] = {};
  for (int k0 = 0; k0 < DIMM; k0 += 32) {
#pragma unroll
    for (int ff = 0; ff < 2; ++ff) {
      int f = threadIdx.x + ff * 256;
      int ar = f >> 3, kq = f & 7;
      int grow = row0 + ar;
      const float* src = (grow < NROWS) ? q : (grow < 2 * NROWS ? k : v);
      int rr = grow & (NROWS - 1);
      float mu = stats[grow * 2], rstd = stats[grow * 2 + 1];
      int gc = k0 + kq * 4;
      float4 x4 = *(const float4*)(src + (size_t)rr * DIMM + gc);
      float4 g4 = *(const float4*)(ln_g + gc);
      float4 b4 = *(const float4*)(ln_b + gc);
      sAT[kq * 4 + 0][ar] = (x4.x - mu) * rstd * g4.x + b4.x;
      sAT[kq * 4 + 1][ar] = (x4.y - mu) * rstd * g4.y + b4.y;
      sAT[kq * 4 + 2][ar] = (x4.z - mu) * rstd * g4.z + b4.z;
      sAT[kq * 4 + 3][ar] = (x4.w - mu) * rstd * g4.w + b4.w;
    }
#pragma unroll
    for (int ff = 0; ff < 2; ++ff) {
      int f = threadIdx.x + ff * 256;
      int kr = f >> 4, cq = f & 15;
      float4 w4 = *(const float4*)(W + (size_t)(k0 + kr) * DIMM + col0 + cq * 4);
      sB[kr][cq * 4 + 0] = w4.x;
      sB[kr][cq * 4 + 1] = w4.y;
      sB[kr][cq * 4 + 2] = w4.z;
      sB[kr][cq * 4 + 3] = w4.w;
    }
    __syncthreads();
#pragma unroll
    for (int kk = 0; kk < 32; ++kk) {
      float4 a4 = *(const float4*)(&sAT[kk][ty * 4]);
      float4 bv = *(const float4*)(&sB[kk][tx * 4]);
      acc[0][0] = fmaf(a4.x, bv.x, acc[0][0]);
      acc[0][1] = fmaf(a4.x, bv.y, acc[0][1]);
      acc[0][2] = fmaf(a4.x, bv.z, acc[0][2]);
      acc[0][3] = fmaf(a4.x, bv.w, acc[0][3]);
      acc[1][0] = fmaf(a4.y, bv.x, acc[1][0]);
      acc[1][1] = fmaf(a4.y, bv.y, acc[1][1]);
      acc[1][2] = fmaf(a4.y, bv.z, acc[1][2]);
      acc[1][3] = fmaf(a4.y, bv.w, acc[1][3]);
      acc[2][0] = fmaf(a4.z, bv.x, acc[2][0]);
      acc[2][1] = fmaf(a4.z, bv.y, acc[2][1]);
      acc[2][2] = fmaf(a4.z, bv.z, acc[2][2]);
      acc[2][3] = fmaf(a4.z, bv.w, acc[2][3]);
      acc[3][0] = fmaf(a4.w, bv.x, acc[3][0]);
      acc[3][1] = fmaf(a4.w, bv.y, acc[3][1]);
      acc[3][2] = fmaf(a4.w, bv.z, acc[3][2]);
      acc[3][3] = fmaf(a4.w, bv.w, acc[3][3]);
    }
    __syncthreads();
  }
#pragma unroll
  for (int i = 0; i < 4; ++i) {
    float4 o;
    o.x = acc[i][0];
    o.y = acc[i][1];
    o.z = acc[i][2];
    o.w = acc[i][3];
    *(float4*)(F + (size_t)(row0 + ty * 4 + i) * DIMM + col0 + tx * 4) = o;
  }
}

// ---------------------------------------------------------------------------
// Kernel 3a: partial column-sums of f_k over 64-row chunks (for kbar)
// grid (32 hq, 16 chunks); 4 waves, wave handles 16 rows, lane = column d.
// ---------------------------------------------------------------------------
__global__ __launch_bounds__(256) void kbar_part_kernel(
    const float* __restrict__ F, float* __restrict__ part) {
  int hq = blockIdx.x, chunk = blockIdx.y;
  int h = hq & 7, g = hq >> 3;
  const float* fk = F + (size_t)NROWS * DIMM + (size_t)g * NTOK * DIMM + h * DHEAD;
  int lane = threadIdx.x & 63, w = threadIdx.x >> 6;
  int base = chunk * 64 + w * 16;
  float s = 0.f;
#pragma unroll
  for (int i = 0; i < 16; ++i) s += fk[(size_t)(base + i) * DIMM + lane];
  __shared__ float sh[4][64];
  sh[w][lane] = s;
  __syncthreads();
  if (threadIdx.x < 64)
    part[(hq * 16 + chunk) * 64 + threadIdx.x] =
        sh[0][threadIdx.x] + sh[1][threadIdx.x] + sh[2][threadIdx.x] + sh[3][threadIdx.x];
}

// ---------------------------------------------------------------------------
// Kernel 3b: finalize kbar[hq][64] and c[hq] = sum_d kbar
// ---------------------------------------------------------------------------
__global__ __launch_bounds__(64) void kbar_fin_kernel(
    const float* __restrict__ part, float* __restrict__ kbar, float* __restrict__ cws) {
  int hq = blockIdx.x, d = threadIdx.x;
  float s = 0.f;
#pragma unroll
  for (int i = 0; i < 16; ++i) s += part[(hq * 16 + i) * 64 + d];
  float kb = s * (1.f / NTOK);
  kbar[hq * 64 + d] = kb;
  float c = kb;
#pragma unroll
  for (int off = 32; off; off >>= 1) c += __shfl_xor(c, off);
  if (d == 0) cws[hq] = c;
}

// ---------------------------------------------------------------------------
// Kernel 3c: per-row stats (coalesced, wave-per-row).
//  per m: n2a = 1/(||f_k||+eps), tma = sum_d f_k
//  per n: n1a = 1/(||f_q||+eps), mua = mean_d f_q, spa = f_q.kbar - mu*c
// grid (32 hq, 16 chunks of 64 rows)
// ---------------------------------------------------------------------------
__global__ __launch_bounds__(256) void rowstats_kernel(
    const float* __restrict__ F, const float* __restrict__ kbar,
    const float* __restrict__ cws, float* __restrict__ n1a,
    float* __restrict__ mua, float* __restrict__ spa,
    float* __restrict__ n2a, float* __restrict__ tma) {
  int hq = blockIdx.x, chunk = blockIdx.y;
  int h = hq & 7, g = hq >> 3;
  const float* fq = F + (size_t)g * NTOK * DIMM + h * DHEAD;
  const float* fk = F + (size_t)NROWS * DIMM + (size_t)g * NTOK * DIMM + h * DHEAD;
  int lane = threadIdx.x & 63, w = threadIdx.x >> 6;
  float kb = kbar[hq * 64 + lane];
  float c = cws[hq];
  int base = chunk * 64 + w * 16;
#pragma unroll 1
  for (int i = 0; i < 16; ++i) {
    int m = base + i;
    float x = fk[(size_t)m * DIMM + lane];
    float s = x, sq = x * x;
#pragma unroll
    for (int off = 32; off; off >>= 1) {
      s += __shfl_xor(s, off);
      sq += __shfl_xor(sq, off);
    }
    if (lane == 0) {
      n2a[hq * NTOK + m] = 1.f / (sqrtf(sq) + COS_EPSF);
      tma[hq * NTOK + m] = s;
    }
  }
#pragma unroll 1
  for (int i = 0; i < 16; ++i) {
    int n = base + i;
    float x = fq[(size_t)n * DIMM + lane];
    float s = x, sq = x * x, sk = x * kb;
#pragma unroll
    for (int off = 32; off; off >>= 1) {
      s += __shfl_xor(s, off);
      sq += __shfl_xor(sq, off);
      sk += __shfl_xor(sk, off);
    }
    if (lane == 0) {
      float mu = s * (1.f / 64.f);
      n1a[hq * NTOK + n] = 1.f / (sqrtf(sq) + COS_EPSF);
      mua[hq * NTOK + n] = mu;
      spa[hq * NTOK + n] = sk - mu * c;
    }
  }
}

// ---------------------------------------------------------------------------
// Kernel 4: fused attention per (h,q). Flash-style over m tiles of 64.
// Block: 256 threads, 32 query rows.
//  Phase S (thread = row r x m-lane ml): scores for mm=ml+8i -> exp -> sE.
//  Phase PV (thread = row r x d-slice ml): o[8] over owned 8 d-columns.
// Q rows held in registers. No running max needed (|score| <= ~0.06).
// var_comp dropped exactly (row-constant => softmax-invariant).
// ---------------------------------------------------------------------------
__global__ __launch_bounds__(256) void attn_kernel(
    const float* __restrict__ F, const float* __restrict__ n1a,
    const float* __restrict__ mua, const float* __restrict__ spa,
    const float* __restrict__ n2a, const float* __restrict__ tma,
    const float* __restrict__ cov_p, const float* __restrict__ var_p,
    float* __restrict__ AO) {
  int hq = blockIdx.y;
  int h = hq & 7, g = hq >> 3;
  int n0 = blockIdx.x * 32;
  const float* fq = F + (size_t)g * NTOK * DIMM + h * DHEAD;
  const float* fk = F + (size_t)NROWS * DIMM + (size_t)g * NTOK * DIMM + h * DHEAD;
  const float* fv = F + 2 * (size_t)NROWS * DIMM + (size_t)g * NTOK * DIMM + h * DHEAD;

  float cov_w = 1.f / (1.f + __expf(-cov_p[0]));
  float var_w = 1.f / (1.f + __expf(-var_p[0]));
  float cos_w = fminf(fmaxf(1.f - cov_w - var_w, 0.1f), 0.8f);
  float half_cos_w = 0.5f * cos_w;
  // cov coeff: 0.5 * cov_w * 0.1 * (LAMBDA/NTOK) * (1/sqrt(64))
  float covf = 0.5f * cov_w * 0.1f * (LAMBDA_REGF / (float)NTOK) * 0.125f;

  __shared__ float sK[64][68];
  __shared__ float sV[64][68];
  __shared__ float sE[32][68];   // Q staging first, then exp-score tile
  __shared__ float sAux[64][2];

  int t = threadIdx.x;
  int r = t >> 3;
  int ml = t & 7;
  int n = n0 + r;

  // stage Q tile (32 rows x 64 cols) into sE, then hoist own row to registers
#pragma unroll
  for (int ff = 0; ff < 2; ++ff) {
    int f = t + ff * 256;
    int rr = f >> 4, cq = f & 15;
    float4 x = *(const float4*)(fq + (size_t)(n0 + rr) * DIMM + cq * 4);
    sE[rr][cq * 4 + 0] = x.x;
    sE[rr][cq * 4 + 1] = x.y;
    sE[rr][cq * 4 + 2] = x.z;
    sE[rr][cq * 4 + 3] = x.w;
  }
  __syncthreads();
  float4 qreg[16];
#pragma unroll
  for (int i = 0; i < 16; ++i) qreg[i] = *(const float4*)(&sE[r][i * 4]);

  float inv_n1 = n1a[hq * NTOK + n];
  float mu = mua[hq * NTOK + n];
  float sp = spa[hq * NTOK + n];

  float osum = 0.f;
  float o[8];
#pragma unroll
  for (int j = 0; j < 8; ++j) o[j] = 0.f;

  for (int m0 = 0; m0 < NTOK; m0 += 64) {
    // load K,V tiles (each 64 rows x 64 cols = 1024 float4)
#pragma unroll
    for (int ff = 0; ff < 4; ++ff) {
      int f = t + ff * 256;
      int mr = f >> 4, cq = f & 15;
      float4 kx = *(const float4*)(fk + (size_t)(m0 + mr) * DIMM + cq * 4);
      sK[mr][cq * 4 + 0] = kx.x;
      sK[mr][cq * 4 + 1] = kx.y;
      sK[mr][cq * 4 + 2] = kx.z;
      sK[mr][cq * 4 + 3] = kx.w;
      float4 vx = *(const float4*)(fv + (size_t)(m0 + mr) * DIMM + cq * 4);
      sV[mr][cq * 4 + 0] = vx.x;
      sV[mr][cq * 4 + 1] = vx.y;
      sV[mr][cq * 4 + 2] = vx.z;
      sV[mr][cq * 4 + 3] = vx.w;
    }
    if (t < 64) {
      sAux[t][0] = n2a[hq * NTOK + m0 + t];
      sAux[t][1] = tma[hq * NTOK + m0 + t];
    }
    __syncthreads();
    // ---- Phase S: 8 scores per thread -> exp -> sE ----
#pragma unroll 1
    for (int i = 0; i < 8; ++i) {
      int mm = ml + 8 * i;
      float dot = 0.f;
#pragma unroll
      for (int j = 0; j < 16; ++j) {
        float4 kx = *(const float4*)(&sK[mm][j * 4]);
        dot = fmaf(qreg[j].x, kx.x, dot);
        dot = fmaf(qreg[j].y, kx.y, dot);
        dot = fmaf(qreg[j].z, kx.z, dot);
        dot = fmaf(qreg[j].w, kx.w, dot);
      }
      float inv_n2 = sAux[mm][0];
      float tm = sAux[mm][1];
      float cs = dot * inv_n1 * inv_n2;
      cs = fminf(fmaxf(cs, -1.f + COS_EPSF), 1.f - COS_EPSF);
      float cov = dot - sp - mu * tm;
      float sc = fmaf(half_cos_w, cs, covf * cov);
      float e = __expf(sc);
      osum += e;
      sE[r][mm] = e;
    }
    __syncthreads();
    // ---- Phase PV: thread owns d = ml*8 .. ml*8+7 ----
#pragma unroll 1
    for (int m = 0; m < 64; ++m) {
      float w = sE[r][m];
      float4 v0 = *(const float4*)(&sV[m][ml * 8]);
      float4 v1 = *(const float4*)(&sV[m][ml * 8 + 4]);
      o[0] = fmaf(w, v0.x, o[0]);
      o[1] = fmaf(w, v0.y, o[1]);
      o[2] = fmaf(w, v0.z, o[2]);
      o[3] = fmaf(w, v0.w, o[3]);
      o[4] = fmaf(w, v1.x, o[4]);
      o[5] = fmaf(w, v1.y, o[5]);
      o[6] = fmaf(w, v1.z, o[6]);
      o[7] = fmaf(w, v1.w, o[7]);
    }
    __syncthreads();
  }
  // row-sum of exp over the 8 m-lane partials (lanes are consecutive in ml)
#pragma unroll
  for (int off = 4; off; off >>= 1) osum += __shfl_xor(osum, off);
  float inv = 1.f / osum;
  float* dst = AO + (size_t)(g * NTOK + n) * DIMM + h * DHEAD + ml * 8;
  float4 w0, w1;
  w0.x = o[0] * inv; w0.y = o[1] * inv; w0.z = o[2] * inv; w0.w = o[3] * inv;
  w1.x = o[4] * inv; w1.y = o[5] * inv; w1.z = o[6] * inv; w1.w = o[7] * inv;
  *(float4*)(dst) = w0;
  *(float4*)(dst + 4) = w1;
}

// ---------------------------------------------------------------------------
// Kernel 5: output GEMM: out[4096][512] = AO @ W_out + b_out
// same sAT-transposed structure as kernel 2
// ---------------------------------------------------------------------------
__global__ __launch_bounds__(256) void out_gemm_kernel(
    const float* __restrict__ A, const float* __restrict__ W,
    const float* __restrict__ bias, float* __restrict__ C) {
  __shared__ float sAT[32][72];
  __shared__ float sB[32][68];
  int row0 = blockIdx.x * 64;
  int col0 = blockIdx.y * 64;
  int tx = threadIdx.x & 15;
  int ty = threadIdx.x >> 4;
  float acc[4][4] = {};
  for (int k0 = 0; k0 < DIMM; k0 += 32) {
#pragma unroll
    for (int ff = 0; ff < 2; ++ff) {
      int f = threadIdx.x + ff * 256;
      int ar = f >> 3, kq = f & 7;
      float4 x4 = *(const float4*)(A + (size_t)(row0 + ar) * DIMM + k0 + kq * 4);
      sAT[kq * 4 + 0][ar] = x4.x;
      sAT[kq * 4 + 1][ar] = x4.y;
      sAT[kq * 4 + 2][ar] = x4.z;
      sAT[kq * 4 + 3][ar] = x4.w;
    }
#pragma unroll
    for (int ff = 0; ff < 2; ++ff) {
      int f = threadIdx.x + ff * 256;
      int kr = f >> 4, cq = f & 15;
      float4 w4 = *(const float4*)(W + (size_t)(k0 + kr) * DIMM + col0 + cq * 4);
      sB[kr][cq * 4 + 0] = w4.x;
      sB[kr][cq * 4 + 1] = w4.y;
      sB[kr][cq * 4 + 2] = w4.z;
      sB[kr][cq * 4 + 3] = w4.w;
    }
    __syncthreads();
#pragma unroll
    for (int kk = 0; kk < 32; ++kk) {
      float4 a4 = *(const float4*)(&sAT[kk][ty * 4]);
      float4 bv = *(const float4*)(&sB[kk][tx * 4]);
      acc[0][0] = fmaf(a4.x, bv.x, acc[0][0]);
      acc[0][1] = fmaf(a4.x, bv.y, acc[0][1]);
      acc[0][2] = fmaf(a4.x, bv.z, acc[0][2]);
      acc[0][3] = fmaf(a4.x, bv.w, acc[0][3]);
      acc[1][0] = fmaf(a4.y, bv.x, acc[1][0]);
      acc[1][1] = fmaf(a4.y, bv.y, acc[1][1]);
      acc[1][2] = fmaf(a4.y, bv.z, acc[1][2]);
      acc[1][3] = fmaf(a4.y, bv.w, acc[1][3]);
      acc[2][0] = fmaf(a4.z, bv.x, acc[2][0]);
      acc[2][1] = fmaf(a4.z, bv.y, acc[2][1]);
      acc[2][2] = fmaf(a4.z, bv.z, acc[2][2]);
      acc[2][3] = fmaf(a4.z, bv.w, acc[2][3]);
      acc[3][0] = fmaf(a4.w, bv.x, acc[3][0]);
      acc[3][1] = fmaf(a4.w, bv.y, acc[3][1]);
      acc[3][2] = fmaf(a4.w, bv.z, acc[3][2]);
      acc[3][3] = fmaf(a4.w, bv.w, acc[3][3]);
    }
    __syncthreads();
  }
#pragma unroll
  for (int i = 0; i < 4; ++i) {
    float4 bb = *(const float4*)(bias + col0 + tx * 4);
    float4 o;
    o.x = acc[i][0] + bb.x;
    o.y = acc[i][1] + bb.y;
    o.z = acc[i][2] + bb.z;
    o.w = acc[i][3] + bb.w;
    *(float4*)(C + (size_t)(row0 + ty * 4 + i) * DIMM + col0 + tx * 4) = o;
  }
}

// ---------------------------------------------------------------------------
extern "C" void kernel_launch(void* const* d_in, const int* in_sizes, int n_in,
                              void* d_out, int out_size, void* d_ws, size_t ws_size,
                              hipStream_t stream) {
  const float* q = (const float*)d_in[0];
  const float* k = (const float*)d_in[1];
  const float* v = (const float*)d_in[2];
  const float* ln_g = (const float*)d_in[3];
  const float* ln_b = (const float*)d_in[4];
  const float* W_in = (const float*)d_in[5];
  const float* cov_p = (const float*)d_in[6];
  const float* var_p = (const float*)d_in[7];
  const float* W_out = (const float*)d_in[8];
  const float* b_out = (const float*)d_in[9];
  float* out = (float*)d_out;

  float* ws = (float*)d_ws;
  float* F = ws;                                  // 12288*512
  float* AO = F + (size_t)MALL * DIMM;            // 4096*512
  float* stats = AO + (size_t)NROWS * DIMM;       // 12288*2
  float* n1a = stats + 2 * MALL;
  float* mua = n1a + 32 * NTOK;
  float* spa = mua + 32 * NTOK;
  float* n2a = spa + 32 * NTOK;
  float* tma = n2a + 32 * NTOK;
  float* kpart = tma + 32 * NTOK;                 // 32*16*64
  float* kbar = kpart + 32 * 16 * 64;             // 32*64
  float* cws = kbar + 32 * 64;                    // 32

  hipLaunchKernelGGL(ln_stats_kernel, dim3(MALL / 4), dim3(256), 0, stream, q, k, v, stats);
  hipLaunchKernelGGL(proj_gemm_kernel, dim3(MALL / 64, DIMM / 64), dim3(256), 0, stream,
                     q, k, v, stats, ln_g, ln_b, W_in, F);
  hipLaunchKernelGGL(kbar_part_kernel, dim3(32, 16), dim3(256), 0, stream, F, kpart);
  hipLaunchKernelGGL(kbar_fin_kernel, dim3(32), dim3(64), 0, stream, kpart, kbar, cws);
  hipLaunchKernelGGL(rowstats_kernel, dim3(32, 16), dim3(256), 0, stream,
                     F, kbar, cws, n1a, mua, spa, n2a, tma);
  hipLaunchKernelGGL(attn_kernel, dim3(NTOK / 32, 32), dim3(256), 0, stream,
                     F, n1a, mua, spa, n2a, tma, cov_p, var_p, AO);
  hipLaunchKernelGGL(out_gemm_kernel, dim3(NROWS / 64, DIMM / 64), dim3(256), 0, stream,
                     AO, W_out, b_out, out);
}

// Round 4
// 267.409 us; speedup vs baseline: 1.9590x; 1.9590x over previous
//
#include <hip/hip_runtime.h>
#include <hip/hip_bf16.h>

#define DIMM 512
#define NHEADS 8
#define DHEAD 64
#define QG 4
#define NTOK 1024
#define NROWS (QG * NTOK)      // 4096
#define MALL (3 * NROWS)       // 12288
#define LN_EPSF 1e-5f
#define COS_EPSF 1e-8f
#define LAMBDA_REGF 0.1f
#define LOG2E 1.4426950408889634f

typedef __bf16 bf16x8 __attribute__((ext_vector_type(8)));
typedef __bf16 bf16x4 __attribute__((ext_vector_type(4)));
typedef float f32x16 __attribute__((ext_vector_type(16)));
typedef float f32x4v __attribute__((ext_vector_type(4)));

// ---------------------------------------------------------------------------
// Kernel 1: LayerNorm row statistics for q,k,v (rows stacked: [q;k;v])
// ---------------------------------------------------------------------------
__global__ __launch_bounds__(256) void ln_stats_kernel(
    const float* __restrict__ q, const float* __restrict__ k,
    const float* __restrict__ v, float* __restrict__ stats) {
  int wave = threadIdx.x >> 6;
  int lane = threadIdx.x & 63;
  int row = blockIdx.x * 4 + wave;
  const float* src = (row < NROWS) ? q : (row < 2 * NROWS ? k : v);
  int r = row & (NROWS - 1);
  const float* p = src + (size_t)r * DIMM;
  float s = 0.f, ss = 0.f;
#pragma unroll
  for (int i = 0; i < DIMM / 64; ++i) {
    float x = p[lane + i * 64];
    s += x;
    ss += x * x;
  }
#pragma unroll
  for (int off = 32; off; off >>= 1) {
    s += __shfl_xor(s, off);
    ss += __shfl_xor(ss, off);
  }
  if (lane == 0) {
    float mu = s * (1.f / DIMM);
    float var = ss * (1.f / DIMM) - mu * mu;
    stats[row * 2] = mu;
    stats[row * 2 + 1] = rsqrtf(var + LN_EPSF);
  }
}

// ---------------------------------------------------------------------------
// Kernel 2: projection GEMM with fused LayerNorm (fp32 compute).
// Output: bf16 Fb[src][h][g][n][64]  (head-major for MFMA attention)
// ---------------------------------------------------------------------------
__global__ __launch_bounds__(256) void proj_gemm_kernel(
    const float* __restrict__ q, const float* __restrict__ k,
    const float* __restrict__ v, const float* __restrict__ stats,
    const float* __restrict__ ln_g, const float* __restrict__ ln_b,
    const float* __restrict__ W, __bf16* __restrict__ Fb) {
  __shared__ float sAT[32][72];
  __shared__ float sB[32][68];
  int row0 = blockIdx.x * 64;
  int col0 = blockIdx.y * 64;
  int tx = threadIdx.x & 15;
  int ty = threadIdx.x >> 4;
  float acc[4][4] = {};
  for (int k0 = 0; k0 < DIMM; k0 += 32) {
#pragma unroll
    for (int ff = 0; ff < 2; ++ff) {
      int f = threadIdx.x + ff * 256;
      int ar = f >> 3, kq = f & 7;
      int grow = row0 + ar;
      const float* src = (grow < NROWS) ? q : (grow < 2 * NROWS ? k : v);
      int rr = grow & (NROWS - 1);
      float mu = stats[grow * 2], rstd = stats[grow * 2 + 1];
      int gc = k0 + kq * 4;
      float4 x4 = *(const float4*)(src + (size_t)rr * DIMM + gc);
      float4 g4 = *(const float4*)(ln_g + gc);
      float4 b4 = *(const float4*)(ln_b + gc);
      sAT[kq * 4 + 0][ar] = (x4.x - mu) * rstd * g4.x + b4.x;
      sAT[kq * 4 + 1][ar] = (x4.y - mu) * rstd * g4.y + b4.y;
      sAT[kq * 4 + 2][ar] = (x4.z - mu) * rstd * g4.z + b4.z;
      sAT[kq * 4 + 3][ar] = (x4.w - mu) * rstd * g4.w + b4.w;
    }
#pragma unroll
    for (int ff = 0; ff < 2; ++ff) {
      int f = threadIdx.x + ff * 256;
      int kr = f >> 4, cq = f & 15;
      float4 w4 = *(const float4*)(W + (size_t)(k0 + kr) * DIMM + col0 + cq * 4);
      sB[kr][cq * 4 + 0] = w4.x;
      sB[kr][cq * 4 + 1] = w4.y;
      sB[kr][cq * 4 + 2] = w4.z;
      sB[kr][cq * 4 + 3] = w4.w;
    }
    __syncthreads();
#pragma unroll
    for (int kk = 0; kk < 32; ++kk) {
      float4 a4 = *(const float4*)(&sAT[kk][ty * 4]);
      float4 bv = *(const float4*)(&sB[kk][tx * 4]);
      acc[0][0] = fmaf(a4.x, bv.x, acc[0][0]);
      acc[0][1] = fmaf(a4.x, bv.y, acc[0][1]);
      acc[0][2] = fmaf(a4.x, bv.z, acc[0][2]);
      acc[0][3] = fmaf(a4.x, bv.w, acc[0][3]);
      acc[1][0] = fmaf(a4.y, bv.x, acc[1][0]);
      acc[1][1] = fmaf(a4.y, bv.y, acc[1][1]);
      acc[1][2] = fmaf(a4.y, bv.z, acc[1][2]);
      acc[1][3] = fmaf(a4.y, bv.w, acc[1][3]);
      acc[2][0] = fmaf(a4.z, bv.x, acc[2][0]);
      acc[2][1] = fmaf(a4.z, bv.y, acc[2][1]);
      acc[2][2] = fmaf(a4.z, bv.z, acc[2][2]);
      acc[2][3] = fmaf(a4.z, bv.w, acc[2][3]);
      acc[3][0] = fmaf(a4.w, bv.x, acc[3][0]);
      acc[3][1] = fmaf(a4.w, bv.y, acc[3][1]);
      acc[3][2] = fmaf(a4.w, bv.z, acc[3][2]);
      acc[3][3] = fmaf(a4.w, bv.w, acc[3][3]);
    }
    __syncthreads();
  }
  // epilogue: bf16 store to Fb[src][h][g][n][64]
  int srci = row0 >> 12;              // block spans one src
  int g = (row0 >> 10) & 3;           // and one g
  int h = col0 >> 6;                  // and one head
  int d0 = tx * 4;
#pragma unroll
  for (int i = 0; i < 4; ++i) {
    int n = (row0 & 1023) + ty * 4 + i;
    bf16x4 o;
    o[0] = (__bf16)acc[i][0];
    o[1] = (__bf16)acc[i][1];
    o[2] = (__bf16)acc[i][2];
    o[3] = (__bf16)acc[i][3];
    *(bf16x4*)(Fb + ((((size_t)srci * 8 + h) * 4 + g) * 1024 + n) * 64 + d0) = o;
  }
}

// ---------------------------------------------------------------------------
// Kernel 2b: transpose f_v  -> FvT[h][g][d][n]  (bf16)
// grid (32 hq, 16 ntile), 256 threads
// ---------------------------------------------------------------------------
__global__ __launch_bounds__(256) void vtrans_kernel(
    const __bf16* __restrict__ Fb, __bf16* __restrict__ FvT) {
  int hq = blockIdx.x;
  int h = hq & 7, g = hq >> 3;
  int n0 = blockIdx.y * 64;
  const __bf16* src = Fb + ((((size_t)2 * 8 + h) * 4 + g) * 1024 + n0) * 64;
  __shared__ __attribute__((aligned(16))) __bf16 sT[64][72];
  int t = threadIdx.x;
#pragma unroll
  for (int ff = 0; ff < 2; ++ff) {
    int f = t + ff * 256;
    int nn = f >> 3, sg = f & 7;
    *(bf16x8*)&sT[nn][sg * 8] = *(const bf16x8*)(src + (size_t)nn * 64 + sg * 8);
  }
  __syncthreads();
  __bf16* dst = FvT + (((size_t)h * 4 + g) * 64) * 1024 + n0;
#pragma unroll
  for (int ff = 0; ff < 2; ++ff) {
    int f = t + ff * 256;
    int d = f >> 3, sg = f & 7;
    bf16x8 vv;
#pragma unroll
    for (int j = 0; j < 8; ++j) vv[j] = sT[sg * 8 + j][d];
    *(bf16x8*)(dst + (size_t)d * 1024 + sg * 8) = vv;
  }
}

// ---------------------------------------------------------------------------
// Kernel 3a: partial column-sums of f_k (bf16 input) for kbar
// ---------------------------------------------------------------------------
__global__ __launch_bounds__(256) void kbar_part_kernel(
    const __bf16* __restrict__ Fb, float* __restrict__ part) {
  int hq = blockIdx.x, chunk = blockIdx.y;
  int h = hq & 7, g = hq >> 3;
  const __bf16* fk = Fb + (((size_t)(8 + h) * 4 + g) * 1024) * 64;
  int lane = threadIdx.x & 63, w = threadIdx.x >> 6;
  int base = chunk * 64 + w * 16;
  float s = 0.f;
#pragma unroll
  for (int i = 0; i < 16; ++i) s += (float)fk[(size_t)(base + i) * 64 + lane];
  __shared__ float sh[4][64];
  sh[w][lane] = s;
  __syncthreads();
  if (threadIdx.x < 64)
    part[(hq * 16 + chunk) * 64 + threadIdx.x] =
        sh[0][threadIdx.x] + sh[1][threadIdx.x] + sh[2][threadIdx.x] + sh[3][threadIdx.x];
}

__global__ __launch_bounds__(64) void kbar_fin_kernel(
    const float* __restrict__ part, float* __restrict__ kbar, float* __restrict__ cws) {
  int hq = blockIdx.x, d = threadIdx.x;
  float s = 0.f;
#pragma unroll
  for (int i = 0; i < 16; ++i) s += part[(hq * 16 + i) * 64 + d];
  float kb = s * (1.f / NTOK);
  kbar[hq * 64 + d] = kb;
  float c = kb;
#pragma unroll
  for (int off = 32; off; off >>= 1) c += __shfl_xor(c, off);
  if (d == 0) cws[hq] = c;
}

// ---------------------------------------------------------------------------
// Kernel 3c: per-row stats from bf16 features (consistent with MFMA dots)
//  n2a = 1/(||f_k||+eps), tma = sum_d f_k ; n1a = 1/(||f_q||+eps), mua, spa
// ---------------------------------------------------------------------------
__global__ __launch_bounds__(256) void rowstats_kernel(
    const __bf16* __restrict__ Fb, const float* __restrict__ kbar,
    const float* __restrict__ cws, float* __restrict__ n1a,
    float* __restrict__ mua, float* __restrict__ spa,
    float* __restrict__ n2a, float* __restrict__ tma) {
  int hq = blockIdx.x, chunk = blockIdx.y;
  int h = hq & 7, g = hq >> 3;
  const __bf16* fq = Fb + (((size_t)(0 + h) * 4 + g) * 1024) * 64;
  const __bf16* fk = Fb + (((size_t)(8 + h) * 4 + g) * 1024) * 64;
  int lane = threadIdx.x & 63, w = threadIdx.x >> 6;
  float kb = kbar[hq * 64 + lane];
  float c = cws[hq];
  int base = chunk * 64 + w * 16;
#pragma unroll 1
  for (int i = 0; i < 16; ++i) {
    int m = base + i;
    float x = (float)fk[(size_t)m * 64 + lane];
    float s = x, sq = x * x;
#pragma unroll
    for (int off = 32; off; off >>= 1) {
      s += __shfl_xor(s, off);
      sq += __shfl_xor(sq, off);
    }
    if (lane == 0) {
      n2a[hq * NTOK + m] = 1.f / (sqrtf(sq) + COS_EPSF);
      tma[hq * NTOK + m] = s;
    }
  }
#pragma unroll 1
  for (int i = 0; i < 16; ++i) {
    int n = base + i;
    float x = (float)fq[(size_t)n * 64 + lane];
    float s = x, sq = x * x, sk = x * kb;
#pragma unroll
    for (int off = 32; off; off >>= 1) {
      s += __shfl_xor(s, off);
      sq += __shfl_xor(sq, off);
      sk += __shfl_xor(sk, off);
    }
    if (lane == 0) {
      float mu = s * (1.f / 64.f);
      n1a[hq * NTOK + n] = 1.f / (sqrtf(sq) + COS_EPSF);
      mua[hq * NTOK + n] = mu;
      spa[hq * NTOK + n] = sk - mu * c;
    }
  }
}

// ---------------------------------------------------------------------------
// Kernel 4: MFMA attention. Per block: (hq, 64-q block). 4 waves.
// wave w: qh = w>>1 (32-q half), mh = w&1 (m-half for S^T, dv-half for PV).
// S^T = K·Q^T via mfma_32x32x16 (scores lane-local in q); exp in-register;
// P -> LDS in MFMA-A-native subtiled layout; PV = P·V from XOR-swizzled V^T.
// Double-buffered K/V^T staged with global_load_lds (pre-swizzled source).
// ---------------------------------------------------------------------------
__global__ __launch_bounds__(256, 2) void attn_mfma_kernel(
    const __bf16* __restrict__ Fb, const __bf16* __restrict__ FvT,
    const float* __restrict__ n1a, const float* __restrict__ mua,
    const float* __restrict__ spa, const float* __restrict__ n2a,
    const float* __restrict__ tma, const float* __restrict__ cov_p,
    const float* __restrict__ var_p, float* __restrict__ AO) {
  int hq = blockIdx.y;
  int h = hq & 7, g = hq >> 3;
  int qb = blockIdx.x;
  int t = threadIdx.x;
  int w = t >> 6;
  int lane = t & 63;
  int l31 = lane & 31;
  int hh = lane >> 5;
  int qh = w >> 1;
  int mh = w & 1;

  const __bf16* fqB = Fb + (((size_t)(0 + h) * 4 + g) * 1024) * 64;
  const __bf16* fkB = Fb + (((size_t)(8 + h) * 4 + g) * 1024) * 64;
  const __bf16* fvT = FvT + (((size_t)h * 4 + g) * 64) * 1024;

  float cov_w = 1.f / (1.f + __expf(-cov_p[0]));
  float var_w = 1.f / (1.f + __expf(-var_p[0]));
  float cos_w = fminf(fmaxf(1.f - cov_w - var_w, 0.1f), 0.8f);
  float HC = 0.5f * cos_w * LOG2E;
  float CV = 0.5f * cov_w * 0.1f * (LAMBDA_REGF / (float)NTOK) * 0.125f * LOG2E;

  int q = qb * 64 + qh * 32 + l31;
  float inv_n1 = n1a[hq * NTOK + q];
  float muq = mua[hq * NTOK + q];
  float spq = spa[hq * NTOK + q];

  // Q B-frags: lane holds Q[q][c*16 + hh*8 .. +7] for c = 0..3
  bf16x8 qf[4];
  {
    const __bf16* qrow = fqB + (size_t)q * 64;
#pragma unroll
    for (int c = 0; c < 4; ++c)
      qf[c] = *(const bf16x8*)(qrow + c * 16 + hh * 8);
  }

  __shared__ __attribute__((aligned(16))) __bf16 sK[2][64][64];
  __shared__ __attribute__((aligned(16))) __bf16 sVT[2][64][64];
  __shared__ __attribute__((aligned(16))) __bf16 Pq[2][8][32][8];
  __shared__ float sOs[2][2][32];

  // stage one 64-m tile (wave w covers rows w*16..w*16+15 of sK and sVT)
  auto stage = [&](int buf, int m0) {
#pragma unroll
    for (int i = 0; i < 2; ++i) {
      int mr = w * 16 + i * 8 + (lane >> 3);
      int cg = lane & 7;
      const __bf16* gp = fkB + (size_t)(m0 + mr) * 64 + ((cg ^ (mr & 7)) * 8);
      __builtin_amdgcn_global_load_lds(
          (const __attribute__((address_space(1))) void*)gp,
          (__attribute__((address_space(3))) void*)&sK[buf][w * 16 + i * 8][0],
          16, 0, 0);
    }
#pragma unroll
    for (int i = 0; i < 2; ++i) {
      int dr = w * 16 + i * 8 + (lane >> 3);
      int cg = lane & 7;
      const __bf16* gp = fvT + (size_t)dr * 1024 + m0 + ((cg ^ (dr & 7)) * 8);
      __builtin_amdgcn_global_load_lds(
          (const __attribute__((address_space(1))) void*)gp,
          (__attribute__((address_space(3))) void*)&sVT[buf][w * 16 + i * 8][0],
          16, 0, 0);
    }
  };

  f32x16 oacc{};
  float osum = 0.f;
  stage(0, 0);
  int cur = 0;
  int mrow = mh * 32 + l31;   // S^T A-frag row (local m)
  int dvr = mh * 32 + l31;    // PV B-frag row (local dv)

  for (int tt = 0; tt < 16; ++tt) {
    __syncthreads();  // staging of buf[cur] complete; Pq free (prev PV done)
    int m0 = tt * 64;
    // ---- S^T = K · Q^T ----
    f32x16 sacc{};
#pragma unroll
    for (int c = 0; c < 4; ++c) {
      bf16x8 af = *(const bf16x8*)&sK[cur][mrow][(((c << 1) | hh) ^ (mrow & 7)) * 8];
      sacc = __builtin_amdgcn_mfma_f32_32x32x16_bf16(af, qf[c], sacc, 0, 0, 0);
    }
    // ---- postproc: scores -> exp -> P (bf16, MFMA-A-native layout) ----
#pragma unroll
    for (int rg = 0; rg < 4; ++rg) {
      int mb = m0 + mh * 32 + rg * 8 + hh * 4;
      f32x4v n2q = *(const f32x4v*)(n2a + hq * NTOK + mb);
      f32x4v tmq = *(const f32x4v*)(tma + hq * NTOK + mb);
      bf16x4 pw;
#pragma unroll
      for (int j = 0; j < 4; ++j) {
        float dot = sacc[rg * 4 + j];
        float cs = dot * (inv_n1 * n2q[j]);
        cs = fminf(fmaxf(cs, -1.f + COS_EPSF), 1.f - COS_EPSF);
        float cov = dot - spq - muq * tmq[j];
        float sc = fmaf(HC, cs, CV * cov);
        float e = exp2f(sc);
        osum += e;
        pw[j] = (__bf16)e;
      }
      *(bf16x4*)&Pq[qh][4 * mh + rg][l31][hh * 4] = pw;
    }
    __syncthreads();  // P complete
    if (tt < 15) stage(cur ^ 1, m0 + 64);  // overlap next-tile staging with PV
    // ---- PV: O[q][dv] += P · V  (wave's dv-half = mh) ----
#pragma unroll
    for (int c = 0; c < 4; ++c) {
      bf16x8 pf = *(const bf16x8*)&Pq[qh][2 * c + hh][l31][0];
      bf16x8 vf = *(const bf16x8*)&sVT[cur][dvr][(((c << 1) | hh) ^ (dvr & 7)) * 8];
      oacc = __builtin_amdgcn_mfma_f32_32x32x16_bf16(pf, vf, oacc, 0, 0, 0);
    }
    cur ^= 1;
  }

  // ---- combine osum across (lane-half, m-half) and write output ----
  osum += __shfl_xor(osum, 32);
  __syncthreads();
  if (lane < 32) sOs[qh][mh][lane] = osum;
  __syncthreads();
#pragma unroll
  for (int rg = 0; rg < 4; ++rg) {
    int ql = rg * 8 + hh * 4;  // local q base of this run
    f32x4v t0 = *(const f32x4v*)&sOs[qh][0][ql];
    f32x4v t1 = *(const f32x4v*)&sOs[qh][1][ql];
#pragma unroll
    for (int j = 0; j < 4; ++j) {
      float inv = 1.f / (t0[j] + t1[j]);
      int qg = qb * 64 + qh * 32 + ql + j;
      AO[((size_t)(g * NTOK + qg)) * DIMM + h * 64 + mh * 32 + l31] =
          oacc[rg * 4 + j] * inv;
    }
  }
}

// ---------------------------------------------------------------------------
// Kernel 5: output GEMM: out[4096][512] = AO @ W_out + b_out (fp32)
// ---------------------------------------------------------------------------
__global__ __launch_bounds__(256) void out_gemm_kernel(
    const float* __restrict__ A, const float* __restrict__ W,
    const float* __restrict__ bias, float* __restrict__ C) {
  __shared__ float sAT[32][72];
  __shared__ float sB[32][68];
  int row0 = blockIdx.x * 64;
  int col0 = blockIdx.y * 64;
  int tx = threadIdx.x & 15;
  int ty = threadIdx.x >> 4;
  float acc[4][4] = {};
  for (int k0 = 0; k0 < DIMM; k0 += 32) {
#pragma unroll
    for (int ff = 0; ff < 2; ++ff) {
      int f = threadIdx.x + ff * 256;
      int ar = f >> 3, kq = f & 7;
      float4 x4 = *(const float4*)(A + (size_t)(row0 + ar) * DIMM + k0 + kq * 4);
      sAT[kq * 4 + 0][ar] = x4.x;
      sAT[kq * 4 + 1][ar] = x4.y;
      sAT[kq * 4 + 2][ar] = x4.z;
      sAT[kq * 4 + 3][ar] = x4.w;
    }
#pragma unroll
    for (int ff = 0; ff < 2; ++ff) {
      int f = threadIdx.x + ff * 256;
      int kr = f >> 4, cq = f & 15;
      float4 w4 = *(const float4*)(W + (size_t)(k0 + kr) * DIMM + col0 + cq * 4);
      sB[kr][cq * 4 + 0] = w4.x;
      sB[kr][cq * 4 + 1] = w4.y;
      sB[kr][cq * 4 + 2] = w4.z;
      sB[kr][cq * 4 + 3] = w4.w;
    }
    __syncthreads();
#pragma unroll
    for (int kk = 0; kk < 32; ++kk) {
      float4 a4 = *(const float4*)(&sAT[kk][ty * 4]);
      float4 bv = *(const float4*)(&sB[kk][tx * 4]);
      acc[0][0] = fmaf(a4.x, bv.x, acc[0][0]);
      acc[0][1] = fmaf(a4.x, bv.y, acc[0][1]);
      acc[0][2] = fmaf(a4.x, bv.z, acc[0][2]);
      acc[0][3] = fmaf(a4.x, bv.w, acc[0][3]);
      acc[1][0] = fmaf(a4.y, bv.x, acc[1][0]);
      acc[1][1] = fmaf(a4.y, bv.y, acc[1][1]);
      acc[1][2] = fmaf(a4.y, bv.z, acc[1][2]);
      acc[1][3] = fmaf(a4.y, bv.w, acc[1][3]);
      acc[2][0] = fmaf(a4.z, bv.x, acc[2][0]);
      acc[2][1] = fmaf(a4.z, bv.y, acc[2][1]);
      acc[2][2] = fmaf(a4.z, bv.z, acc[2][2]);
      acc[2][3] = fmaf(a4.z, bv.w, acc[2][3]);
      acc[3][0] = fmaf(a4.w, bv.x, acc[3][0]);
      acc[3][1] = fmaf(a4.w, bv.y, acc[3][1]);
      acc[3][2] = fmaf(a4.w, bv.z, acc[3][2]);
      acc[3][3] = fmaf(a4.w, bv.w, acc[3][3]);
    }
    __syncthreads();
  }
#pragma unroll
  for (int i = 0; i < 4; ++i) {
    float4 bb = *(const float4*)(bias + col0 + tx * 4);
    float4 o;
    o.x = acc[i][0] + bb.x;
    o.y = acc[i][1] + bb.y;
    o.z = acc[i][2] + bb.z;
    o.w = acc[i][3] + bb.w;
    *(float4*)(C + (size_t)(row0 + ty * 4 + i) * DIMM + col0 + tx * 4) = o;
  }
}

// ---------------------------------------------------------------------------
extern "C" void kernel_launch(void* const* d_in, const int* in_sizes, int n_in,
                              void* d_out, int out_size, void* d_ws, size_t ws_size,
                              hipStream_t stream) {
  const float* q = (const float*)d_in[0];
  const float* k = (const float*)d_in[1];
  const float* v = (const float*)d_in[2];
  const float* ln_g = (const float*)d_in[3];
  const float* ln_b = (const float*)d_in[4];
  const float* W_in = (const float*)d_in[5];
  const float* cov_p = (const float*)d_in[6];
  const float* var_p = (const float*)d_in[7];
  const float* W_out = (const float*)d_in[8];
  const float* b_out = (const float*)d_in[9];
  float* out = (float*)d_out;

  float* ws = (float*)d_ws;
  __bf16* Fb = (__bf16*)ws;                          // 3*8*4*1024*64 bf16 = 3145728 floats
  __bf16* FvT = (__bf16*)(ws + 3145728);             // 8*4*64*1024 bf16 = 1048576 floats
  float* AO = ws + 3145728 + 1048576;                // 4096*512 f32
  float* stats = AO + (size_t)NROWS * DIMM;          // 24576
  float* n1a = stats + 2 * MALL;
  float* mua = n1a + 32 * NTOK;
  float* spa = mua + 32 * NTOK;
  float* n2a = spa + 32 * NTOK;
  float* tma = n2a + 32 * NTOK;
  float* kpart = tma + 32 * NTOK;                    // 32*16*64
  float* kbar = kpart + 32 * 16 * 64;                // 32*64
  float* cws = kbar + 32 * 64;                       // 32

  hipLaunchKernelGGL(ln_stats_kernel, dim3(MALL / 4), dim3(256), 0, stream, q, k, v, stats);
  hipLaunchKernelGGL(proj_gemm_kernel, dim3(MALL / 64, DIMM / 64), dim3(256), 0, stream,
                     q, k, v, stats, ln_g, ln_b, W_in, Fb);
  hipLaunchKernelGGL(vtrans_kernel, dim3(32, 16), dim3(256), 0, stream, Fb, FvT);
  hipLaunchKernelGGL(kbar_part_kernel, dim3(32, 16), dim3(256), 0, stream, Fb, kpart);
  hipLaunchKernelGGL(kbar_fin_kernel, dim3(32), dim3(64), 0, stream, kpart, kbar, cws);
  hipLaunchKernelGGL(rowstats_kernel, dim3(32, 16), dim3(256), 0, stream,
                     Fb, kbar, cws, n1a, mua, spa, n2a, tma);
  hipLaunchKernelGGL(attn_mfma_kernel, dim3(16, 32), dim3(256), 0, stream,
                     Fb, FvT, n1a, mua, spa, n2a, tma, cov_p, var_p, AO);
  hipLaunchKernelGGL(out_gemm_kernel, dim3(NROWS / 64, DIMM / 64), dim3(256), 0, stream,
                     AO, W_out, b_out, out);
}

// Round 9
// 200.856 us; speedup vs baseline: 2.6081x; 1.3313x over previous
//
#include <hip/hip_runtime.h>
#include <hip/hip_bf16.h>

#define DIMM 512
#define NHEADS 8
#define DHEAD 64
#define QG 4
#define NTOK 1024
#define NROWS (QG * NTOK)      // 4096
#define MALL (3 * NROWS)       // 12288
#define LN_EPSF 1e-5f
#define COS_EPSF 1e-8f
#define LAMBDA_REGF 0.1f
#define LOG2E 1.4426950408889634f

typedef __bf16 bf16x8 __attribute__((ext_vector_type(8)));
typedef __bf16 bf16x4 __attribute__((ext_vector_type(4)));
typedef float f32x16 __attribute__((ext_vector_type(16)));
typedef float f32x4v __attribute__((ext_vector_type(4)));

// ---------------------------------------------------------------------------
// Kernel 1: LayerNorm row statistics for q,k,v (rows stacked: [q;k;v])
// ---------------------------------------------------------------------------
__global__ __launch_bounds__(256) void ln_stats_kernel(
    const float* __restrict__ q, const float* __restrict__ k,
    const float* __restrict__ v, float* __restrict__ stats) {
  int wave = threadIdx.x >> 6;
  int lane = threadIdx.x & 63;
  int row = blockIdx.x * 4 + wave;
  const float* src = (row < NROWS) ? q : (row < 2 * NROWS ? k : v);
  int r = row & (NROWS - 1);
  const float* p = src + (size_t)r * DIMM;
  float s = 0.f, ss = 0.f;
#pragma unroll
  for (int i = 0; i < DIMM / 64; ++i) {
    float x = p[lane + i * 64];
    s += x;
    ss += x * x;
  }
#pragma unroll
  for (int off = 32; off; off >>= 1) {
    s += __shfl_xor(s, off);
    ss += __shfl_xor(ss, off);
  }
  if (lane == 0) {
    float mu = s * (1.f / DIMM);
    float var = ss * (1.f / DIMM) - mu * mu;
    stats[row * 2] = mu;
    stats[row * 2 + 1] = rsqrtf(var + LN_EPSF);
  }
}

// ---------------------------------------------------------------------------
// Kernel 2a: weight prep.  z=0: WbT[n][k] = bf16(ln_g[k]*W_in[k][n])
//                          z=1: WoT[n][k] = bf16(W_out[k][n])
// ---------------------------------------------------------------------------
__global__ __launch_bounds__(256) void wprep_kernel(
    const float* __restrict__ W_in, const float* __restrict__ W_out,
    const float* __restrict__ ln_g, __bf16* __restrict__ WbT,
    __bf16* __restrict__ WoT) {
  int z = blockIdx.z;
  const float* src = z ? W_out : W_in;
  __bf16* dst = z ? WoT : WbT;
  int bi = blockIdx.x;  // k tile (rows of W)
  int bj = blockIdx.y;  // n tile (cols of W)
  __shared__ float sTr[64][65];
  int t = threadIdx.x;
  int r = t >> 2;
  int qq = t & 3;
  float gr = z ? 1.f : ln_g[bi * 64 + r];
#pragma unroll
  for (int i = 0; i < 4; ++i) {
    float4 x = *(const float4*)(src + (size_t)(bi * 64 + r) * 512 + bj * 64 + (qq * 4 + i) * 4);
    sTr[r][qq * 16 + i * 4 + 0] = x.x * gr;
    sTr[r][qq * 16 + i * 4 + 1] = x.y * gr;
    sTr[r][qq * 16 + i * 4 + 2] = x.z * gr;
    sTr[r][qq * 16 + i * 4 + 3] = x.w * gr;
  }
  __syncthreads();
#pragma unroll
  for (int ff = 0; ff < 2; ++ff) {
    int f = t + ff * 256;
    int c = f >> 3, gq = f & 7;
    bf16x8 vv;
#pragma unroll
    for (int j = 0; j < 8; ++j) vv[j] = (__bf16)sTr[gq * 8 + j][c];
    *(bf16x8*)(dst + (size_t)(bj * 64 + c) * 512 + bi * 64 + gq * 8) = vv;
  }
}

// ---------------------------------------------------------------------------
// Kernel 2b: bbias[n] = sum_k ln_b[k] * W_in[k][n]
// ---------------------------------------------------------------------------
__global__ __launch_bounds__(256) void bbias_kernel(
    const float* __restrict__ ln_b, const float* __restrict__ W_in,
    float* __restrict__ bbias) {
  int n = blockIdx.x * 256 + threadIdx.x;
  float s = 0.f;
  for (int k = 0; k < 512; ++k) s = fmaf(ln_b[k], W_in[(size_t)k * 512 + n], s);
  bbias[n] = s;
}

// ---------------------------------------------------------------------------
// Kernel 3: projection via bf16 MFMA, fused LN on A-staging.
// Fb[src][h][g][n][64] = bf16( ((x-mu)*rstd) @ WbT^T + bbias )
// block: 64 rows x 64 cols (one head), 4 waves 2x2, K-steps of 64, dbuf.
// ---------------------------------------------------------------------------
__global__ __launch_bounds__(256) void proj_mfma_kernel(
    const float* __restrict__ q, const float* __restrict__ k,
    const float* __restrict__ v, const float* __restrict__ stats,
    const __bf16* __restrict__ WbT, const float* __restrict__ bbias,
    __bf16* __restrict__ Fb) {
  int h = blockIdx.x;           // col tile / head
  int by = blockIdx.y;          // row tile
  int row0 = by * 64;
  int col0 = h * 64;
  int t = threadIdx.x;
  int w = t >> 6, lane = t & 63, l31 = lane & 31, hh = lane >> 5;
  int wr = w >> 1, wc = w & 1;

  __shared__ __attribute__((aligned(16))) __bf16 sA[2][64][72];
  __shared__ __attribute__((aligned(16))) __bf16 sB[2][64][72];

  // A staging: thread -> row ar, 16 consecutive k (4 float4)
  int ar = t >> 2, aq = t & 3;
  int grow = row0 + ar;
  const float* asrc = (grow < NROWS) ? q : (grow < 2 * NROWS ? k : v);
  int arr = grow & (NROWS - 1);
  float amu = stats[grow * 2], arstd = stats[grow * 2 + 1];
  const float* aptr = asrc + (size_t)arr * DIMM + aq * 16;

  // B staging: thread -> 2 x (col, 8 k) chunks
  int bc0 = t >> 3, bg0 = t & 7;
  const __bf16* bptr0 = WbT + (size_t)(col0 + bc0) * 512 + bg0 * 8;
  const __bf16* bptr1 = WbT + (size_t)(col0 + bc0 + 32) * 512 + bg0 * 8;

  float4 ra[4];
  bf16x8 rb0, rb1;

  auto LOAD = [&](int kt) {
#pragma unroll
    for (int i = 0; i < 4; ++i) ra[i] = *(const float4*)(aptr + kt * 64 + 4 * i);
    rb0 = *(const bf16x8*)(bptr0 + kt * 64);
    rb1 = *(const bf16x8*)(bptr1 + kt * 64);
  };
  auto WRITE = [&](int buf) {
    bf16x8 w0, w1;
    w0[0] = (__bf16)((ra[0].x - amu) * arstd);
    w0[1] = (__bf16)((ra[0].y - amu) * arstd);
    w0[2] = (__bf16)((ra[0].z - amu) * arstd);
    w0[3] = (__bf16)((ra[0].w - amu) * arstd);
    w0[4] = (__bf16)((ra[1].x - amu) * arstd);
    w0[5] = (__bf16)((ra[1].y - amu) * arstd);
    w0[6] = (__bf16)((ra[1].z - amu) * arstd);
    w0[7] = (__bf16)((ra[1].w - amu) * arstd);
    w1[0] = (__bf16)((ra[2].x - amu) * arstd);
    w1[1] = (__bf16)((ra[2].y - amu) * arstd);
    w1[2] = (__bf16)((ra[2].z - amu) * arstd);
    w1[3] = (__bf16)((ra[2].w - amu) * arstd);
    w1[4] = (__bf16)((ra[3].x - amu) * arstd);
    w1[5] = (__bf16)((ra[3].y - amu) * arstd);
    w1[6] = (__bf16)((ra[3].z - amu) * arstd);
    w1[7] = (__bf16)((ra[3].w - amu) * arstd);
    *(bf16x8*)&sA[buf][ar][aq * 16] = w0;
    *(bf16x8*)&sA[buf][ar][aq * 16 + 8] = w1;
    *(bf16x8*)&sB[buf][bc0][bg0 * 8] = rb0;
    *(bf16x8*)&sB[buf][bc0 + 32][bg0 * 8] = rb1;
  };

  f32x16 acc{};
  LOAD(0);
  WRITE(0);
  int cur = 0;
  for (int kt = 0; kt < 8; ++kt) {
    __syncthreads();
    if (kt < 7) LOAD(kt + 1);
#pragma unroll
    for (int ks = 0; ks < 4; ++ks) {
      bf16x8 af = *(const bf16x8*)&sA[cur][wr * 32 + l31][ks * 16 + hh * 8];
      bf16x8 bfr = *(const bf16x8*)&sB[cur][wc * 32 + l31][ks * 16 + hh * 8];
      acc = __builtin_amdgcn_mfma_f32_32x32x16_bf16(af, bfr, acc, 0, 0, 0);
    }
    if (kt < 7) {
      WRITE(cur ^ 1);
      cur ^= 1;
    }
  }
  // epilogue: add bbias, store bf16 to Fb[src][h][g][n][64]
  int srci = row0 >> 12;
  int g = (row0 >> 10) & 3;
  int nbase = (row0 & 1023) + wr * 32;
  float bb = bbias[col0 + wc * 32 + l31];
  __bf16* fout = Fb + ((((size_t)srci * 8 + h) * 4 + g) * 1024 + nbase) * 64 + wc * 32 + l31;
#pragma unroll
  for (int rg = 0; rg < 16; ++rg) {
    int row = (rg & 3) + 8 * (rg >> 2) + 4 * hh;
    fout[(size_t)row * 64] = (__bf16)(acc[rg] + bb);
  }
}

// ---------------------------------------------------------------------------
// Kernel 3b: transpose f_v -> FvT[h][g][d][n]  (bf16)
// ---------------------------------------------------------------------------
__global__ __launch_bounds__(256) void vtrans_kernel(
    const __bf16* __restrict__ Fb, __bf16* __restrict__ FvT) {
  int hq = blockIdx.x;
  int h = hq & 7, g = hq >> 3;
  int n0 = blockIdx.y * 64;
  const __bf16* src = Fb + ((((size_t)2 * 8 + h) * 4 + g) * 1024 + n0) * 64;
  __shared__ __attribute__((aligned(16))) __bf16 sT[64][72];
  int t = threadIdx.x;
#pragma unroll
  for (int ff = 0; ff < 2; ++ff) {
    int f = t + ff * 256;
    int nn = f >> 3, sg = f & 7;
    *(bf16x8*)&sT[nn][sg * 8] = *(const bf16x8*)(src + (size_t)nn * 64 + sg * 8);
  }
  __syncthreads();
  __bf16* dst = FvT + (((size_t)h * 4 + g) * 64) * 1024 + n0;
#pragma unroll
  for (int ff = 0; ff < 2; ++ff) {
    int f = t + ff * 256;
    int d = f >> 3, sg = f & 7;
    bf16x8 vv;
#pragma unroll
    for (int j = 0; j < 8; ++j) vv[j] = sT[sg * 8 + j][d];
    *(bf16x8*)(dst + (size_t)d * 1024 + sg * 8) = vv;
  }
}

// ---------------------------------------------------------------------------
// Kernel 4a/4b: kbar (column means of f_k) in two stages
// ---------------------------------------------------------------------------
__global__ __launch_bounds__(256) void kbar_part_kernel(
    const __bf16* __restrict__ Fb, float* __restrict__ part) {
  int hq = blockIdx.x, chunk = blockIdx.y;
  int h = hq & 7, g = hq >> 3;
  const __bf16* fk = Fb + (((size_t)(8 + h) * 4 + g) * 1024) * 64;
  int lane = threadIdx.x & 63, w = threadIdx.x >> 6;
  int base = chunk * 64 + w * 16;
  float s = 0.f;
#pragma unroll
  for (int i = 0; i < 16; ++i) s += (float)fk[(size_t)(base + i) * 64 + lane];
  __shared__ float sh[4][64];
  sh[w][lane] = s;
  __syncthreads();
  if (threadIdx.x < 64)
    part[(hq * 16 + chunk) * 64 + threadIdx.x] =
        sh[0][threadIdx.x] + sh[1][threadIdx.x] + sh[2][threadIdx.x] + sh[3][threadIdx.x];
}

__global__ __launch_bounds__(64) void kbar_fin_kernel(
    const float* __restrict__ part, float* __restrict__ kbar, float* __restrict__ cws) {
  int hq = blockIdx.x, d = threadIdx.x;
  float s = 0.f;
#pragma unroll
  for (int i = 0; i < 16; ++i) s += part[(hq * 16 + i) * 64 + d];
  float kb = s * (1.f / NTOK);
  kbar[hq * 64 + d] = kb;
  float c = kb;
#pragma unroll
  for (int off = 32; off; off >>= 1) c += __shfl_xor(c, off);
  if (d == 0) cws[hq] = c;
}

// ---------------------------------------------------------------------------
// Kernel 4c: per-row stats from bf16 features
// ---------------------------------------------------------------------------
__global__ __launch_bounds__(256) void rowstats_kernel(
    const __bf16* __restrict__ Fb, const float* __restrict__ kbar,
    const float* __restrict__ cws, float* __restrict__ n1a,
    float* __restrict__ mua, float* __restrict__ spa,
    float* __restrict__ n2a, float* __restrict__ tma) {
  int hq = blockIdx.x, chunk = blockIdx.y;
  int h = hq & 7, g = hq >> 3;
  const __bf16* fq = Fb + (((size_t)(0 + h) * 4 + g) * 1024) * 64;
  const __bf16* fk = Fb + (((size_t)(8 + h) * 4 + g) * 1024) * 64;
  int lane = threadIdx.x & 63, w = threadIdx.x >> 6;
  float kb = kbar[hq * 64 + lane];
  float c = cws[hq];
  int base = chunk * 64 + w * 16;
#pragma unroll 1
  for (int i = 0; i < 16; ++i) {
    int m = base + i;
    float x = (float)fk[(size_t)m * 64 + lane];
    float s = x, sq = x * x;
#pragma unroll
    for (int off = 32; off; off >>= 1) {
      s += __shfl_xor(s, off);
      sq += __shfl_xor(sq, off);
    }
    if (lane == 0) {
      n2a[hq * NTOK + m] = 1.f / (sqrtf(sq) + COS_EPSF);
      tma[hq * NTOK + m] = s;
    }
  }
#pragma unroll 1
  for (int i = 0; i < 16; ++i) {
    int n = base + i;
    float x = (float)fq[(size_t)n * 64 + lane];
    float s = x, sq = x * x, sk = x * kb;
#pragma unroll
    for (int off = 32; off; off >>= 1) {
      s += __shfl_xor(s, off);
      sq += __shfl_xor(sq, off);
      sk += __shfl_xor(sk, off);
    }
    if (lane == 0) {
      float mu = s * (1.f / 64.f);
      n1a[hq * NTOK + n] = 1.f / (sqrtf(sq) + COS_EPSF);
      mua[hq * NTOK + n] = mu;
      spa[hq * NTOK + n] = sk - mu * c;
    }
  }
}

// ---------------------------------------------------------------------------
// Kernel 5: MFMA attention (validated structure; output bf16 AOb)
// ---------------------------------------------------------------------------
__global__ __launch_bounds__(256, 2) void attn_mfma_kernel(
    const __bf16* __restrict__ Fb, const __bf16* __restrict__ FvT,
    const float* __restrict__ n1a, const float* __restrict__ mua,
    const float* __restrict__ spa, const float* __restrict__ n2a,
    const float* __restrict__ tma, const float* __restrict__ cov_p,
    const float* __restrict__ var_p, __bf16* __restrict__ AOb) {
  int hq = blockIdx.y;
  int h = hq & 7, g = hq >> 3;
  int qb = blockIdx.x;
  int t = threadIdx.x;
  int w = t >> 6;
  int lane = t & 63;
  int l31 = lane & 31;
  int hh = lane >> 5;
  int qh = w >> 1;
  int mh = w & 1;

  const __bf16* fqB = Fb + (((size_t)(0 + h) * 4 + g) * 1024) * 64;
  const __bf16* fkB = Fb + (((size_t)(8 + h) * 4 + g) * 1024) * 64;
  const __bf16* fvT = FvT + (((size_t)h * 4 + g) * 64) * 1024;

  float cov_w = 1.f / (1.f + __expf(-cov_p[0]));
  float var_w = 1.f / (1.f + __expf(-var_p[0]));
  float cos_w = fminf(fmaxf(1.f - cov_w - var_w, 0.1f), 0.8f);
  float HC = 0.5f * cos_w * LOG2E;
  float CV = 0.5f * cov_w * 0.1f * (LAMBDA_REGF / (float)NTOK) * 0.125f * LOG2E;

  int q = qb * 64 + qh * 32 + l31;
  float inv_n1 = n1a[hq * NTOK + q];
  float muq = mua[hq * NTOK + q];
  float spq = spa[hq * NTOK + q];

  bf16x8 qf[4];
  {
    const __bf16* qrow = fqB + (size_t)q * 64;
#pragma unroll
    for (int c = 0; c < 4; ++c)
      qf[c] = *(const bf16x8*)(qrow + c * 16 + hh * 8);
  }

  __shared__ __attribute__((aligned(16))) __bf16 sK[2][64][64];
  __shared__ __attribute__((aligned(16))) __bf16 sVT[2][64][64];
  __shared__ __attribute__((aligned(16))) __bf16 Pq[2][8][32][8];
  __shared__ float sOs[2][2][32];

  auto stage = [&](int buf, int m0) {
#pragma unroll
    for (int i = 0; i < 2; ++i) {
      int mr = w * 16 + i * 8 + (lane >> 3);
      int cg = lane & 7;
      const __bf16* gp = fkB + (size_t)(m0 + mr) * 64 + ((cg ^ (mr & 7)) * 8);
      __builtin_amdgcn_global_load_lds(
          (const __attribute__((address_space(1))) void*)gp,
          (__attribute__((address_space(3))) void*)&sK[buf][w * 16 + i * 8][0],
          16, 0, 0);
    }
#pragma unroll
    for (int i = 0; i < 2; ++i) {
      int dr = w * 16 + i * 8 + (lane >> 3);
      int cg = lane & 7;
      const __bf16* gp = fvT + (size_t)dr * 1024 + m0 + ((cg ^ (dr & 7)) * 8);
      __builtin_amdgcn_global_load_lds(
          (const __attribute__((address_space(1))) void*)gp,
          (__attribute__((address_space(3))) void*)&sVT[buf][w * 16 + i * 8][0],
          16, 0, 0);
    }
  };

  f32x16 oacc{};
  float osum = 0.f;
  stage(0, 0);
  int cur = 0;
  int mrow = mh * 32 + l31;
  int dvr = mh * 32 + l31;

  for (int tt = 0; tt < 16; ++tt) {
    __syncthreads();
    int m0 = tt * 64;
    f32x16 sacc{};
#pragma unroll
    for (int c = 0; c < 4; ++c) {
      bf16x8 af = *(const bf16x8*)&sK[cur][mrow][(((c << 1) | hh) ^ (mrow & 7)) * 8];
      sacc = __builtin_amdgcn_mfma_f32_32x32x16_bf16(af, qf[c], sacc, 0, 0, 0);
    }
#pragma unroll
    for (int rg = 0; rg < 4; ++rg) {
      int mb = m0 + mh * 32 + rg * 8 + hh * 4;
      f32x4v n2q = *(const f32x4v*)(n2a + hq * NTOK + mb);
      f32x4v tmq = *(const f32x4v*)(tma + hq * NTOK + mb);
      bf16x4 pw;
#pragma unroll
      for (int j = 0; j < 4; ++j) {
        float dot = sacc[rg * 4 + j];
        float cs = dot * (inv_n1 * n2q[j]);
        cs = fminf(fmaxf(cs, -1.f + COS_EPSF), 1.f - COS_EPSF);
        float cov = dot - spq - muq * tmq[j];
        float sc = fmaf(HC, cs, CV * cov);
        float e = exp2f(sc);
        osum += e;
        pw[j] = (__bf16)e;
      }
      *(bf16x4*)&Pq[qh][4 * mh + rg][l31][hh * 4] = pw;
    }
    __syncthreads();
    if (tt < 15) stage(cur ^ 1, m0 + 64);
#pragma unroll
    for (int c = 0; c < 4; ++c) {
      bf16x8 pf = *(const bf16x8*)&Pq[qh][2 * c + hh][l31][0];
      bf16x8 vf = *(const bf16x8*)&sVT[cur][dvr][(((c << 1) | hh) ^ (dvr & 7)) * 8];
      oacc = __builtin_amdgcn_mfma_f32_32x32x16_bf16(pf, vf, oacc, 0, 0, 0);
    }
    cur ^= 1;
  }

  osum += __shfl_xor(osum, 32);
  __syncthreads();
  if (lane < 32) sOs[qh][mh][lane] = osum;
  __syncthreads();
#pragma unroll
  for (int rg = 0; rg < 4; ++rg) {
    int ql = rg * 8 + hh * 4;
    f32x4v t0 = *(const f32x4v*)&sOs[qh][0][ql];
    f32x4v t1 = *(const f32x4v*)&sOs[qh][1][ql];
#pragma unroll
    for (int j = 0; j < 4; ++j) {
      float inv = 1.f / (t0[j] + t1[j]);
      int qg = qb * 64 + qh * 32 + ql + j;
      AOb[((size_t)(g * NTOK + qg)) * DIMM + h * 64 + mh * 32 + l31] =
          (__bf16)(oacc[rg * 4 + j] * inv);
    }
  }
}

// ---------------------------------------------------------------------------
// Kernel 6: output GEMM via bf16 MFMA: out = AOb @ WoT^T + b_out (fp32 out)
// ---------------------------------------------------------------------------
__global__ __launch_bounds__(256) void out_mfma_kernel(
    const __bf16* __restrict__ AOb, const __bf16* __restrict__ WoT,
    const float* __restrict__ b_out, float* __restrict__ out) {
  int h = blockIdx.x;       // col tile
  int by = blockIdx.y;      // row tile
  int row0 = by * 64;
  int col0 = h * 64;
  int t = threadIdx.x;
  int w = t >> 6, lane = t & 63, l31 = lane & 31, hh = lane >> 5;
  int wr = w >> 1, wc = w & 1;

  __shared__ __attribute__((aligned(16))) __bf16 sA[2][64][72];
  __shared__ __attribute__((aligned(16))) __bf16 sB[2][64][72];

  int ac0 = t >> 3, ag0 = t & 7;
  const __bf16* aptr0 = AOb + (size_t)(row0 + ac0) * 512 + ag0 * 8;
  const __bf16* aptr1 = AOb + (size_t)(row0 + ac0 + 32) * 512 + ag0 * 8;
  const __bf16* bptr0 = WoT + (size_t)(col0 + ac0) * 512 + ag0 * 8;
  const __bf16* bptr1 = WoT + (size_t)(col0 + ac0 + 32) * 512 + ag0 * 8;

  bf16x8 ra0, ra1, rb0, rb1;
  auto LOAD = [&](int kt) {
    ra0 = *(const bf16x8*)(aptr0 + kt * 64);
    ra1 = *(const bf16x8*)(aptr1 + kt * 64);
    rb0 = *(const bf16x8*)(bptr0 + kt * 64);
    rb1 = *(const bf16x8*)(bptr1 + kt * 64);
  };
  auto WRITE = [&](int buf) {
    *(bf16x8*)&sA[buf][ac0][ag0 * 8] = ra0;
    *(bf16x8*)&sA[buf][ac0 + 32][ag0 * 8] = ra1;
    *(bf16x8*)&sB[buf][ac0][ag0 * 8] = rb0;
    *(bf16x8*)&sB[buf][ac0 + 32][ag0 * 8] = rb1;
  };

  f32x16 acc{};
  LOAD(0);
  WRITE(0);
  int cur = 0;
  for (int kt = 0; kt < 8; ++kt) {
    __syncthreads();
    if (kt < 7) LOAD(kt + 1);
#pragma unroll
    for (int ks = 0; ks < 4; ++ks) {
      bf16x8 af = *(const bf16x8*)&sA[cur][wr * 32 + l31][ks * 16 + hh * 8];
      bf16x8 bfr = *(const bf16x8*)&sB[cur][wc * 32 + l31][ks * 16 + hh * 8];
      acc = __builtin_amdgcn_mfma_f32_32x32x16_bf16(af, bfr, acc, 0, 0, 0);
    }
    if (kt < 7) {
      WRITE(cur ^ 1);
      cur ^= 1;
    }
  }
  float bo = b_out[col0 + wc * 32 + l31];
  float* po = out + (size_t)(row0 + wr * 32) * 512 + col0 + wc * 32 + l31;
#pragma unroll
  for (int rg = 0; rg < 16; ++rg) {
    int row = (rg & 3) + 8 * (rg >> 2) + 4 * hh;
    po[(size_t)row * 512] = acc[rg] + bo;
  }
}

// ---------------------------------------------------------------------------
extern "C" void kernel_launch(void* const* d_in, const int* in_sizes, int n_in,
                              void* d_out, int out_size, void* d_ws, size_t ws_size,
                              hipStream_t stream) {
  const float* q = (const float*)d_in[0];
  const float* k = (const float*)d_in[1];
  const float* v = (const float*)d_in[2];
  const float* ln_g = (const float*)d_in[3];
  const float* ln_b = (const float*)d_in[4];
  const float* W_in = (const float*)d_in[5];
  const float* cov_p = (const float*)d_in[6];
  const float* var_p = (const float*)d_in[7];
  const float* W_out = (const float*)d_in[8];
  const float* b_out = (const float*)d_in[9];
  float* out = (float*)d_out;

  float* ws = (float*)d_ws;
  __bf16* Fb = (__bf16*)ws;                         // 6291456 bf16
  __bf16* FvT = (__bf16*)(ws + 3145728);            // 2097152 bf16
  __bf16* AOb = (__bf16*)(ws + 3145728 + 1048576);  // 2097152 bf16
  __bf16* WbT = (__bf16*)(ws + 5242880);            // 262144 bf16
  __bf16* WoT = (__bf16*)(ws + 5373952);            // 262144 bf16
  float* bbias = ws + 5505024;                      // 512
  float* stats = bbias + 512;                       // 24576
  float* n1a = stats + 2 * MALL;
  float* mua = n1a + 32 * NTOK;
  float* spa = mua + 32 * NTOK;
  float* n2a = spa + 32 * NTOK;
  float* tma = n2a + 32 * NTOK;
  float* kpart = tma + 32 * NTOK;                   // 32*16*64
  float* kbar = kpart + 32 * 16 * 64;               // 32*64
  float* cws = kbar + 32 * 64;                      // 32

  hipLaunchKernelGGL(ln_stats_kernel, dim3(MALL / 4), dim3(256), 0, stream, q, k, v, stats);
  hipLaunchKernelGGL(wprep_kernel, dim3(8, 8, 2), dim3(256), 0, stream,
                     W_in, W_out, ln_g, WbT, WoT);
  hipLaunchKernelGGL(bbias_kernel, dim3(2), dim3(256), 0, stream, ln_b, W_in, bbias);
  hipLaunchKernelGGL(proj_mfma_kernel, dim3(8, MALL / 64), dim3(256), 0, stream,
                     q, k, v, stats, WbT, bbias, Fb);
  hipLaunchKernelGGL(vtrans_kernel, dim3(32, 16), dim3(256), 0, stream, Fb, FvT);
  hipLaunchKernelGGL(kbar_part_kernel, dim3(32, 16), dim3(256), 0, stream, Fb, kpart);
  hipLaunchKernelGGL(kbar_fin_kernel, dim3(32), dim3(64), 0, stream, kpart, kbar, cws);
  hipLaunchKernelGGL(rowstats_kernel, dim3(32, 16), dim3(256), 0, stream,
                     Fb, kbar, cws, n1a, mua, spa, n2a, tma);
  hipLaunchKernelGGL(attn_mfma_kernel, dim3(16, 32), dim3(256), 0, stream,
                     Fb, FvT, n1a, mua, spa, n2a, tma, cov_p, var_p, AOb);
  hipLaunchKernelGGL(out_mfma_kernel, dim3(8, NROWS / 64), dim3(256), 0, stream,
                     AOb, WoT, b_out, out);
}